// Round 7
// baseline (126.352 us; speedup 1.0000x reference)
//
#include <hip/hip_runtime.h>

#define SRC_LEN 256
#define TRG_LEN 256
#define BATCH   32
#define HID     512
#define ATT     128
#define CSCALE  2.885390081777927f   // 2*log2(e): exp2(CSCALE*x) == exp(2x)

typedef float  f32x4  __attribute__((ext_vector_type(4)));
typedef short  bf16x8 __attribute__((ext_vector_type(8)));

// manual RNE fp32->bf16 (inputs are finite normals; NaN path not needed)
__device__ inline unsigned short bfr(float x) {
    unsigned u = __builtin_bit_cast(unsigned, x);
    return (unsigned short)((u + 0x7fffu + ((u >> 16) & 1u)) >> 16);
}
__device__ inline unsigned pk2(float a, float b) {
    return (unsigned)bfr(a) | ((unsigned)bfr(b) << 16);
}

// ---------------------------------------------------------------------------
// Prep: W_s/W_t -> bf16 MFMA-B fragments in global (R2's verified algebra:
// for a_tile, chunk c, half s, lane l holds W[a_tile*16+(l&15)][c*64+s*32+
// (l>>4)*8+j], j=0..7). Proj then loads each B-fragment as ONE coalesced
// dwordx4; the 128 KB/side working set is L2-resident across all blocks.
// ---------------------------------------------------------------------------
__global__ __launch_bounds__(256) void prep_kernel(
    const float* __restrict__ W_s, const float* __restrict__ W_t,
    uint4* __restrict__ Wb)
{
    const int blk = blockIdx.x;               // 0..15
    const int iw = blk >> 3, a_tile = blk & 7;
    const float* __restrict__ W = iw ? W_t : W_s;
    uint4* __restrict__ dst = Wb + ((size_t)iw * 8 + a_tile) * 1024;
    #pragma unroll
    for (int oo = 0; oo < 4; ++oo) {
        const int o = threadIdx.x + oo * 256;  // (c*2+s)*64 + lane
        const int c = o >> 7, rem = o & 127;
        const int s = rem >> 6, lane = rem & 63;
        const int q = lane >> 4, l15 = lane & 15;
        const int row = a_tile * 16 + l15;
        const int k0 = c * 64 + s * 32 + q * 8;
        const float4 f0 = *(const float4*)(W + (size_t)row * HID + k0);
        const float4 f1 = *(const float4*)(W + (size_t)row * HID + k0 + 4);
        uint4 u;
        u.x = pk2(f0.x, f0.y); u.y = pk2(f0.z, f0.w);
        u.z = pk2(f1.x, f1.y); u.w = pk2(f1.z, f1.w);
        dst[o] = u;
    }
}

// ---------------------------------------------------------------------------
// Proj v12: BARRIER-FREE main loop. R6 ledger: proj ~29 us vs ~6.5 us HBM
// roofline = ~90% exposed latency, structural to the per-chunk
// vmcnt(0)+__syncthreads lockstep (MFMA/chunk ~40cyc vs HBM ~600-900cyc;
// R1 showed more blocks with the same barriers doesn't help).
// Fix: no LDS staging at all.
//  - A: per-lane direct global loads matching the A-fragment mapping
//    (row=l&15, k=(l>>4)*8+j): 2 dwordx4 per fragment, in-register pk2.
//    Chunk A-slice = 4 KB/block, L1-resident; all 4 waves read the SAME
//    16 rows -> L1 amortizes the 16-way row scatter.
//  - B: prebuilt Wb fragments, 1 coalesced dwordx4 each, L2-resident.
// Fully-unrolled 8-chunk loop; A-offsets fold into 13-bit immediates.
// 1024 blocks x 256 thr = 4 waves/SIMD of uncorrelated progress.
// b is the FAST grid digit (XCD write->read locality for score v11).
// Wave w covers rows r0..r0+15 x cols w*32..+31 (2 mfma frags).
// ---------------------------------------------------------------------------
__global__ __launch_bounds__(256, 4) void proj_mfma(
    const float* __restrict__ dec_out, const float* __restrict__ enc_outs,
    const float* __restrict__ b_t, const uint4* __restrict__ Wb,
    float* __restrict__ encE, float* __restrict__ decD)
{
    __shared__ __align__(16) float T[16 * 132];   // enc epilogue transpose only

    const int tid   = threadIdx.x;
    const int blk   = blockIdx.x;
    const bool isDec = blk >= 512;
    const int blkL  = isDec ? blk - 512 : blk;
    const int bb    = blkL & 31;                  // FAST digit -> XCD = b%8
    const int r0    = (blkL >> 5) * 16;           // s0 or t0
    const float* __restrict__ in = isDec ? dec_out : enc_outs;
    const uint4* __restrict__ Wk = Wb + (isDec ? 8192 : 0);

    const int lane = tid & 63;
    const int w    = tid >> 6;                    // 0..3
    const int woff_n = w * 32;
    const int q = lane >> 4, l15 = lane & 15;

    // per-lane A base: row r0+l15, batch bb, k-offset q*8
    const float* __restrict__ aBase =
        in + ((size_t)(r0 + l15) * BATCH + bb) * HID + q * 8;

    f32x4 acc[2];
    acc[0] = (f32x4)0.0f;
    acc[1] = (f32x4)0.0f;

    #pragma unroll
    for (int c = 0; c < 8; ++c) {
        #pragma unroll
        for (int s = 0; s < 2; ++s) {
            const int k = c * 64 + s * 32;        // + q*8 already in aBase
            const float4 f0 = *(const float4*)(aBase + k);
            const float4 f1 = *(const float4*)(aBase + k + 4);
            uint4 ua;
            ua.x = pk2(f0.x, f0.y); ua.y = pk2(f0.z, f0.w);
            ua.z = pk2(f1.x, f1.y); ua.w = pk2(f1.z, f1.w);
            const bf16x8 af = __builtin_bit_cast(bf16x8, ua);
            #pragma unroll
            for (int ni = 0; ni < 2; ++ni) {
                const int a_tile = w * 2 + ni;
                const bf16x8 bfv = *(const bf16x8*)(
                    Wk + (((a_tile * 8 + c) * 2 + s) * 64 + lane));
                acc[ni] = __builtin_amdgcn_mfma_f32_16x16x32_bf16(
                    af, bfv, acc[ni], 0, 0, 0);
            }
        }
    }

    if (!isDec) {
        // F = exp(+2*enc_att) -> LDS transpose (stride 132) -> [b][a>>2][s][4]
        #pragma unroll
        for (int ni = 0; ni < 2; ++ni)
            #pragma unroll
            for (int r = 0; r < 4; ++r) {
                const int ml = q * 4 + r;               // 0..15 (s-local)
                const int nl = woff_n + ni * 16 + l15;  // 0..127 (a)
                T[ml * 132 + nl] = __builtin_amdgcn_exp2f(CSCALE * acc[ni][r]);
            }
        __syncthreads();
        {
            const int m  = tid & 15;     // s-local
            const int g0 = tid >> 4;     // 0..15
            #pragma unroll
            for (int p = 0; p < 2; ++p) {
                const int gq = g0 + p * 16;             // a-quad 0..31
                float4 v = *(const float4*)(T + m * 132 + gq * 4);
                *(float4*)(encE + (((size_t)bb * 32 + gq) * SRC_LEN + r0 + m) * 4) = v;
            }
        }
    } else {
        // D = exp(+2*(dec_att + b_t)), natural [t][b][a] store
        float bt[2];
        bt[0] = b_t[woff_n + l15];
        bt[1] = b_t[woff_n + 16 + l15];
        #pragma unroll
        for (int ni = 0; ni < 2; ++ni)
            #pragma unroll
            for (int r = 0; r < 4; ++r) {
                const int ml = q * 4 + r;
                const int nl = woff_n + ni * 16 + l15;
                decD[((size_t)(r0 + ml) * BATCH + bb) * ATT + nl] =
                    __builtin_amdgcn_exp2f(CSCALE * (acc[ni][r] + bt[ni]));
            }
    }
}

// ---------------------------------------------------------------------------
// Score v11 (UNCHANGED — part of the best-measured 114.4 total):
// b-fast grid (XCD write->read locality) + F-form rational
// term = v/(1+F*d); d,v via LDS broadcast; encE one dwordx4 per g.
// ---------------------------------------------------------------------------
__global__ __launch_bounds__(256) void score_kernel(
    const float* __restrict__ encE, const float* __restrict__ decD,
    const float* __restrict__ v_a, float* __restrict__ out)
{
    __shared__ float dS[4 * ATT];
    __shared__ float vS[ATT];
    __shared__ float sumvS;

    const int tid = threadIdx.x;
    const int b   = blockIdx.x;          // FAST dim -> XCD = b%8 (matches proj)
    const int t0  = blockIdx.y * 4;

    if (tid < 128) {
        const int tt = tid >> 5, a4 = (tid & 31) * 4;
        *(float4*)(dS + tt * ATT + a4) =
            *(const float4*)(decD + ((size_t)(t0 + tt) * BATCH + b) * ATT + a4);
    } else if (tid < 160) {
        const int l = tid - 128;
        *(float4*)(vS + l * 4) = *(const float4*)(v_a + l * 4);
    }
    __syncthreads();
    if (tid < 64) {
        float x = vS[tid] + vS[tid + 64];
        #pragma unroll
        for (int o = 32; o > 0; o >>= 1) x += __shfl_down(x, o);
        if (tid == 0) sumvS = x;
    }
    __syncthreads();

    float acc0 = 0.f, acc1 = 0.f, acc2 = 0.f, acc3 = 0.f;
    const float* __restrict__ ep = encE + ((size_t)b * 32 * SRC_LEN + tid) * 4;

    #pragma unroll
    for (int g = 0; g < 32; ++g) {
        const float4 F  = *(const float4*)(ep + (size_t)g * SRC_LEN * 4);
        const float4 vv = *(const float4*)(vS + g * 4);

        #define TSTEP(ACC, DBASE)                                          \
        {                                                                  \
            const float4 d = *(const float4*)(DBASE + g * 4);              \
            const float y0 = fmaf(F.x, d.x, 1.0f);                         \
            const float y1 = fmaf(F.y, d.y, 1.0f);                         \
            const float y2 = fmaf(F.z, d.z, 1.0f);                         \
            const float y3 = fmaf(F.w, d.w, 1.0f);                         \
            const float a01 = y0 * y1, a23 = y2 * y3;                      \
            const float den = a01 * a23;                                   \
            const float m01 = fmaf(vv.x, y1, vv.y * y0);                   \
            const float m23 = fmaf(vv.z, y3, vv.w * y2);                   \
            const float num = fmaf(m01, a23, m23 * a01);                   \
            ACC = fmaf(num, __builtin_amdgcn_rcpf(den), ACC);              \
        }
        TSTEP(acc0, dS + 0 * ATT)
        TSTEP(acc1, dS + 1 * ATT)
        TSTEP(acc2, dS + 2 * ATT)
        TSTEP(acc3, dS + 3 * ATT)
        #undef TSTEP
    }

    const float sv = sumvS;
    out[((size_t)(t0 + 0) * BATCH + b) * SRC_LEN + tid] = sv - 2.0f * acc0;
    out[((size_t)(t0 + 1) * BATCH + b) * SRC_LEN + tid] = sv - 2.0f * acc1;
    out[((size_t)(t0 + 2) * BATCH + b) * SRC_LEN + tid] = sv - 2.0f * acc2;
    out[((size_t)(t0 + 3) * BATCH + b) * SRC_LEN + tid] = sv - 2.0f * acc3;
}

extern "C" void kernel_launch(void* const* d_in, const int* in_sizes, int n_in,
                              void* d_out, int out_size, void* d_ws, size_t ws_size,
                              hipStream_t stream) {
    const float* dec_out  = (const float*)d_in[0];
    const float* enc_outs = (const float*)d_in[1];
    const float* W_s      = (const float*)d_in[2];
    const float* W_t      = (const float*)d_in[3];
    const float* b_t      = (const float*)d_in[4];
    const float* v_a      = (const float*)d_in[5];
    float* out = (float*)d_out;

    float* encE = (float*)d_ws;                              // B*32*S*4 = 4 MB : exp(+2*enc_att), [b][a>>2][s][4]
    float* decD = encE + (size_t)BATCH * ATT * SRC_LEN;      // T*B*A    = 4 MB : exp(+2*dec_att), [t][b][a]
    uint4* Wb   = (uint4*)(decD + (size_t)TRG_LEN * BATCH * ATT);  // 256 KB bf16 W fragments

    prep_kernel<<<16, 256, 0, stream>>>(W_s, W_t, Wb);
    proj_mfma<<<1024, 256, 0, stream>>>(dec_out, enc_outs, b_t, Wb, encE, decD);
    score_kernel<<<dim3(BATCH, TRG_LEN / 4), 256, 0, stream>>>(encE, decD, v_a, out);
}

// Round 8
// 114.557 us; speedup vs baseline: 1.1030x; 1.1030x over previous
//
#include <hip/hip_runtime.h>

#define SRC_LEN 256
#define TRG_LEN 256
#define BATCH   32
#define HID     512
#define ATT     128
#define CSCALE  2.885390081777927f   // 2*log2(e): exp2(CSCALE*x) == exp(2x)

typedef float  f32x4  __attribute__((ext_vector_type(4)));
typedef float  f32x2  __attribute__((ext_vector_type(2)));
typedef short  bf16x8 __attribute__((ext_vector_type(8)));

// manual RNE fp32->bf16 (inputs are finite normals; NaN path not needed)
__device__ inline unsigned short bfr(float x) {
    unsigned u = __builtin_bit_cast(unsigned, x);
    return (unsigned short)((u + 0x7fffu + ((u >> 16) & 1u)) >> 16);
}
__device__ inline unsigned pk2(float a, float b) {
    return (unsigned)bfr(a) | ((unsigned)bfr(b) << 16);
}

// ---------------------------------------------------------------------------
// MFMA projection v5-F (EXACT R6 build, part of best-measured 114.4 total):
// 64 rows x 128 a tile, K=512 in 8 chunks, 256 blocks x 512 threads,
// validated LDS swizzle + coalesced staging; enc epilogue stores
// F = exp(+2*enc_att). b is the FAST block digit (XCD = b%8).
// R1/R2/R7 all proved restructures regress — do not touch.
// ---------------------------------------------------------------------------
__global__ __launch_bounds__(512) void proj_mfma(
    const float* __restrict__ dec_out, const float* __restrict__ enc_outs,
    const float* __restrict__ W_s, const float* __restrict__ W_t,
    const float* __restrict__ b_t,
    float* __restrict__ encE, float* __restrict__ decD)
{
    __shared__ __align__(16) char smem[49152];
    char* aLb = smem;            // [2][64 rows][128 B] = 16 KB
    char* bLb = smem + 16384;    // [2][128 rows][128 B] = 32 KB

    const int tid   = threadIdx.x;
    const int blk   = blockIdx.x;
    const bool isDec = blk >= 128;
    const int bb    = blk & 31;
    const int r0    = ((isDec ? blk - 128 : blk) >> 5) * 64;  // s0 or t0
    const float* __restrict__ in = isDec ? dec_out : enc_outs;
    const float* __restrict__ W  = isDec ? W_t : W_s;

    const int lane   = tid & 63;
    const int w      = tid >> 6;        // 0..7
    const int woff_m = (w & 3) * 16;
    const int woff_n = (w >> 2) * 64;
    const int q      = lane >> 4;
    const int l15    = lane & 15;
    const int l7     = lane & 7;

    const int srow = tid >> 4;
    const int skc  = tid & 15;
    const int sg   = skc >> 1, shalf = skc & 1;
    const float* aGp = in + ((size_t)(r0 + srow) * BATCH + bb) * HID + skc * 4;
    const float* wGp = W + (size_t)srow * HID + skc * 4;

    float4 aR[2];   // A rows srow, srow+32
    float4 wR[4];   // W rows srow + it*32

    f32x4 acc[4];
    #pragma unroll
    for (int ni = 0; ni < 4; ++ni) acc[ni] = (f32x4)0.0f;

    #define LOADG(c)                                                          \
        {                                                                     \
            _Pragma("unroll")                                                 \
            for (int it = 0; it < 2; ++it)                                    \
                aR[it] = *(const float4*)(aGp + (size_t)it * 32 * BATCH * HID \
                                          + (c) * 64);                        \
            _Pragma("unroll")                                                 \
            for (int it = 0; it < 4; ++it)                                    \
                wR[it] = *(const float4*)(wGp + (size_t)it * 32 * HID         \
                                          + (c) * 64);                        \
        }

    #define STORES(buf)                                                      \
        {                                                                    \
            char* ab = aLb + (buf) * 8192;                                   \
            _Pragma("unroll")                                                \
            for (int it = 0; it < 2; ++it) {                                 \
                const int i = srow + it * 32;                                \
                uint2 u;                                                     \
                u.x = pk2(aR[it].x, aR[it].y);                               \
                u.y = pk2(aR[it].z, aR[it].w);                               \
                *(uint2*)(ab + i * 128 + ((sg ^ (i & 7)) << 4)               \
                          + shalf * 8) = u;                                  \
            }                                                                \
            char* bp = bLb + (buf) * 16384;                                  \
            _Pragma("unroll")                                                \
            for (int it = 0; it < 4; ++it) {                                 \
                const int rw = srow + it * 32;                               \
                uint2 u;                                                     \
                u.x = pk2(wR[it].x, wR[it].y);                               \
                u.y = pk2(wR[it].z, wR[it].w);                               \
                *(uint2*)(bp + rw * 128 + ((sg ^ (rw & 7)) << 4)             \
                          + shalf * 8) = u;                                  \
            }                                                                \
        }

    LOADG(0);
    STORES(0);
    __syncthreads();

    for (int c = 0; c < 8; ++c) {
        if (c < 7) LOADG(c + 1);
        const char* ab = aLb + (c & 1) * 8192;
        const char* bp = bLb + (c & 1) * 16384;
        #pragma unroll
        for (int s = 0; s < 2; ++s) {
            const int sw = ((s * 4 + q) ^ l7) * 16;
            bf16x8 af = *(const bf16x8*)(ab + (woff_m + l15) * 128 + sw);
            bf16x8 bfv[4];
            #pragma unroll
            for (int ni = 0; ni < 4; ++ni)
                bfv[ni] = *(const bf16x8*)(bp + (woff_n + ni * 16 + l15) * 128 + sw);
            #pragma unroll
            for (int ni = 0; ni < 4; ++ni)
                acc[ni] = __builtin_amdgcn_mfma_f32_16x16x32_bf16(
                    af, bfv[ni], acc[ni], 0, 0, 0);
        }
        if (c < 7) STORES((c + 1) & 1);
        __syncthreads();
    }

    if (!isDec) {
        // F = exp(+2*enc_att) -> LDS transpose (stride 132, float4-aligned)
        // -> [b][a>>2][s][4] store: one coalesced float4 per lane for score.
        float* T = (float*)smem;
        #pragma unroll
        for (int ni = 0; ni < 4; ++ni)
            #pragma unroll
            for (int r = 0; r < 4; ++r) {
                const int ml = woff_m + q * 4 + r;
                const int nl = woff_n + ni * 16 + l15;
                T[ml * 132 + nl] = __builtin_amdgcn_exp2f(CSCALE * acc[ni][r]);
            }
        __syncthreads();
        {
            const int m  = tid & 63;     // s-local
            const int g0 = tid >> 6;     // 0..7
            #pragma unroll
            for (int p = 0; p < 4; ++p) {
                const int gq = g0 + p * 8;          // a-quad 0..31
                float4 v = *(const float4*)(T + m * 132 + gq * 4);
                *(float4*)(encE + (((size_t)bb * 32 + gq) * SRC_LEN + r0 + m) * 4) = v;
            }
        }
    } else {
        // D = exp(+2*(dec_att + b_t)), natural [t][b][a] store
        float bt[4];
        #pragma unroll
        for (int ni = 0; ni < 4; ++ni) bt[ni] = b_t[woff_n + ni * 16 + l15];
        #pragma unroll
        for (int ni = 0; ni < 4; ++ni)
            #pragma unroll
            for (int r = 0; r < 4; ++r) {
                const int ml = woff_m + q * 4 + r;
                const int nl = woff_n + ni * 16 + l15;
                decD[((size_t)(r0 + ml) * BATCH + bb) * ATT + nl] =
                    __builtin_amdgcn_exp2f(CSCALE * (acc[ni][r] + bt[ni]));
            }
    }
    #undef LOADG
    #undef STORES
}

// ---------------------------------------------------------------------------
// Score v12 = v11 (b-fast grid + F-form, both in the measured-best 114.4
// build) + packed-fp32 t-pair math (R1-validated structure, never isolated):
// every y/a01/den/m01/m23/num/acc op becomes ONE v_pk_* instruction over the
// t-pair (F, v broadcast via op_sel — free; only d differs per t). Main-loop
// VALU issue ~30 -> ~17 slots per 2 t (~-45%). d staged interleaved
// dPf[pair][a][2] so packed operands come straight from ds_read (same LDS
// instruction count as v11). Only the 2 rcps stay scalar.
// ---------------------------------------------------------------------------
__global__ __launch_bounds__(256) void score_kernel(
    const float* __restrict__ encE, const float* __restrict__ decD,
    const float* __restrict__ v_a, float* __restrict__ out)
{
    __shared__ __align__(16) float dPf[2][ATT][2];   // [pair][a][tEven/tOdd]
    __shared__ float vS[ATT];
    __shared__ float sumvS;

    const int tid = threadIdx.x;
    const int b   = blockIdx.x;          // FAST dim -> XCD = b%8 (matches proj)
    const int t0  = blockIdx.y * 4;

    if (tid < 64) {
        const int pr = tid >> 5, a4 = (tid & 31) * 4;
        const float4 dA = *(const float4*)(decD + ((size_t)(t0 + 2 * pr) * BATCH + b) * ATT + a4);
        const float4 dB = *(const float4*)(decD + ((size_t)(t0 + 2 * pr + 1) * BATCH + b) * ATT + a4);
        f32x2* dst = (f32x2*)&dPf[pr][a4][0];
        dst[0] = (f32x2){dA.x, dB.x};
        dst[1] = (f32x2){dA.y, dB.y};
        dst[2] = (f32x2){dA.z, dB.z};
        dst[3] = (f32x2){dA.w, dB.w};
    } else if (tid < 96) {
        const int l = tid - 64;
        *(float4*)(vS + l * 4) = *(const float4*)(v_a + l * 4);
    }
    __syncthreads();
    if (tid < 64) {
        float x = vS[tid] + vS[tid + 64];
        #pragma unroll
        for (int o = 32; o > 0; o >>= 1) x += __shfl_down(x, o);
        if (tid == 0) sumvS = x;
    }
    __syncthreads();

    f32x2 acc0 = {0.f, 0.f};
    f32x2 acc1 = {0.f, 0.f};
    const float* __restrict__ ep = encE + ((size_t)b * 32 * SRC_LEN + tid) * 4;

    #pragma unroll
    for (int g = 0; g < 32; ++g) {
        const float4 F  = *(const float4*)(ep + (size_t)g * SRC_LEN * 4);
        const float4 vv = *(const float4*)(vS + g * 4);
        const f32x2 F0 = {F.x, F.x}, F1 = {F.y, F.y};
        const f32x2 F2 = {F.z, F.z}, F3 = {F.w, F.w};
        const f32x2 v0 = {vv.x, vv.x}, v1 = {vv.y, vv.y};
        const f32x2 v2 = {vv.z, vv.z}, v3 = {vv.w, vv.w};
        const f32x2 one = {1.f, 1.f};

        #define PSTEP(ACC, PR)                                             \
        {                                                                  \
            const f32x2* dp = (const f32x2*)&dPf[PR][g * 4][0];            \
            const f32x2 y0 = F0 * dp[0] + one;                             \
            const f32x2 y1 = F1 * dp[1] + one;                             \
            const f32x2 y2 = F2 * dp[2] + one;                             \
            const f32x2 y3 = F3 * dp[3] + one;                             \
            const f32x2 a01 = y0 * y1, a23 = y2 * y3;                      \
            const f32x2 den = a01 * a23;                                   \
            const f32x2 m01 = v0 * y1 + v1 * y0;                           \
            const f32x2 m23 = v2 * y3 + v3 * y2;                           \
            const f32x2 num = m01 * a23 + m23 * a01;                       \
            f32x2 r;                                                       \
            r[0] = __builtin_amdgcn_rcpf(den[0]);                          \
            r[1] = __builtin_amdgcn_rcpf(den[1]);                          \
            ACC += num * r;                                                \
        }
        PSTEP(acc0, 0)
        PSTEP(acc1, 1)
        #undef PSTEP
    }

    const float sv = sumvS;
    out[((size_t)(t0 + 0) * BATCH + b) * SRC_LEN + tid] = sv - 2.0f * acc0[0];
    out[((size_t)(t0 + 1) * BATCH + b) * SRC_LEN + tid] = sv - 2.0f * acc0[1];
    out[((size_t)(t0 + 2) * BATCH + b) * SRC_LEN + tid] = sv - 2.0f * acc1[0];
    out[((size_t)(t0 + 3) * BATCH + b) * SRC_LEN + tid] = sv - 2.0f * acc1[1];
}

extern "C" void kernel_launch(void* const* d_in, const int* in_sizes, int n_in,
                              void* d_out, int out_size, void* d_ws, size_t ws_size,
                              hipStream_t stream) {
    const float* dec_out  = (const float*)d_in[0];
    const float* enc_outs = (const float*)d_in[1];
    const float* W_s      = (const float*)d_in[2];
    const float* W_t      = (const float*)d_in[3];
    const float* b_t      = (const float*)d_in[4];
    const float* v_a      = (const float*)d_in[5];
    float* out = (float*)d_out;

    float* encE = (float*)d_ws;                              // B*32*S*4 = 4 MB : exp(+2*enc_att), [b][a>>2][s][4]
    float* decD = encE + (size_t)BATCH * ATT * SRC_LEN;      // T*B*A    = 4 MB : exp(+2*dec_att), [t][b][a]

    proj_mfma<<<256, 512, 0, stream>>>(dec_out, enc_outs, W_s, W_t, b_t, encE, decD);

    // grid: b fast (XCD = b%8, matching proj's writes), t-blocks slow
    score_kernel<<<dim3(BATCH, TRG_LEN / 4), 256, 0, stream>>>(encE, decD, v_a, out);
}